// Round 8
// baseline (379.395 us; speedup 1.0000x reference)
//
#include <hip/hip_runtime.h>
#include <hip/hip_bf16.h>
#include <math.h>

#define L_SEQ 8192
#define DM 1024
#define DI 2048
#define NH 32
#define HD 64
#define DS 128
#define CDIM 2304
#define DPROJ 4384
#define NPAD_IN 4480  // 35*128, zero-padded W_in rows
#define KSPLIT 32
#define OPROWS 2176   // 2048 Vs^T rows + 128 B^T rows

typedef short bf16x8 __attribute__((ext_vector_type(8)));
typedef float floatx16 __attribute__((ext_vector_type(16)));
typedef unsigned short u16x4 __attribute__((ext_vector_type(4)));
typedef unsigned short u16x8 __attribute__((ext_vector_type(8)));

#define AS1(p) ((const __attribute__((address_space(1))) void*)(p))
#define AS3(p) ((__attribute__((address_space(3))) void*)(p))

__device__ __forceinline__ float bf2f(unsigned short u) {
  union { unsigned int i; float f; } c; c.i = ((unsigned int)u) << 16; return c.f;
}
__device__ __forceinline__ unsigned short f2bf(float f) {
  return __bfloat16_as_ushort(__float2bfloat16(f));
}

// ---------------------------------------------------------------------------
// bf16 MFMA GEMM: C[m,n] = sum_k A[m,k]*B[n,k]  (K contiguous both operands)
// 128x128 tile, BK=32, 4 waves (2x2), each wave 2x2 frags of 32x32x16
// (m119: 32x32 runs at 2495 TF vs 2176 for 16x16 — 17% better pipe rate,
//  half the MFMA instruction count for the same ds_read traffic).
// XCD-aware swizzle (modes 0/1/3, gy==64): linear id round-robins over 8 XCDs;
// map xcd=linear&7 to an 8-m-row band, m-fastest within n (r6: FETCH 219->60MB).
// All modes use LDS-repacked coalesced epilogues (no partial-line RFO):
// MODE 0: bf16 out, ushort8 sweep, 8-col-run guard (Nstore % 8 == 0).
// MODE 1: bf16 out, ushort8 sweep, fused + Dvec[gcol>>6]*bf16(xs[...]).
// MODE 2: f32 out, float4 sweep, split-K (blockIdx.z -> K-chunk & slice).
// MODE 3: f32 out, float4 sweep (grid must cover N exactly).
// ---------------------------------------------------------------------------
template <int MODE>
__global__ __launch_bounds__(256)
void gemm_bt_mfma(const unsigned short* __restrict__ A, int lda,
                  const unsigned short* __restrict__ B, int ldb,
                  void* __restrict__ Cout, int ldc,
                  int Kfull, int Nstore,
                  const unsigned short* __restrict__ xs,
                  const float* __restrict__ Dvec) {
  __shared__ __align__(16) char smem[17408];  // staging 16 KB; f32 repack 17 KB
  unsigned short* Asm = (unsigned short*)smem;
  unsigned short* Bsm = Asm + 128 * 32;
  const int t = threadIdx.x;

  int bx = blockIdx.x, by = blockIdx.y;
  if (MODE != 2) {
    int gx = gridDim.x;
    int linear = by * gx + bx;
    int xcd = linear & 7;
    int local = linear >> 3;
    by = xcd * 8 + (local & 7);
    bx = local >> 3;
  }
  const int m0 = by * 128;
  const int n0 = bx * 128;

  int kstart = 0, klen = Kfull;
  if (MODE == 2) { klen = Kfull / KSPLIT; kstart = blockIdx.z * klen; }
  const int wave = t >> 6, lane = t & 63;
  const int wm = (wave & 1) * 64;
  const int wn = (wave >> 1) * 64;
  const int r31 = lane & 31;        // frag row/col within 32
  const int kq8 = (lane >> 5) * 8;  // input k sub-offset
  const int rbase = (lane >> 5) * 4;  // C/D row base component

  floatx16 acc[2][2];
#pragma unroll
  for (int i = 0; i < 2; ++i)
#pragma unroll
    for (int j = 0; j < 2; ++j)
#pragma unroll
      for (int e = 0; e < 16; ++e) acc[i][j][e] = 0.f;

  for (int k0 = kstart; k0 < kstart + klen; k0 += 32) {
#pragma unroll
    for (int i = 0; i < 2; ++i) {
      int linear = i * 256 + t;          // 0..511
      int row = linear >> 2;             // 0..127
      int kq = (linear & 3) * 8;         // bf16 elem offset in K
      const unsigned short* ga = A + (size_t)(m0 + row) * lda + (k0 + kq);
      const unsigned short* gb = B + (size_t)(n0 + row) * ldb + (k0 + kq);
      __builtin_amdgcn_global_load_lds(AS1(ga), AS3(&Asm[linear * 8]), 16, 0, 0);
      __builtin_amdgcn_global_load_lds(AS1(gb), AS3(&Bsm[linear * 8]), 16, 0, 0);
    }
    __syncthreads();

    // A[m][k]: m = r31 (+32*mi +wm), k = kb*16 + kq8 + j   (B symmetric)
    bf16x8 af[2][2], bfv[2][2];
#pragma unroll
    for (int mi = 0; mi < 2; ++mi)
#pragma unroll
      for (int kb = 0; kb < 2; ++kb) {
        af[mi][kb]  = *(const bf16x8*)&Asm[(wm + mi * 32 + r31) * 32 + kb * 16 + kq8];
        bfv[mi][kb] = *(const bf16x8*)&Bsm[(wn + mi * 32 + r31) * 32 + kb * 16 + kq8];
      }
#pragma unroll
    for (int kb = 0; kb < 2; ++kb)
#pragma unroll
      for (int mi = 0; mi < 2; ++mi)
#pragma unroll
        for (int ni = 0; ni < 2; ++ni)
          acc[mi][ni] = __builtin_amdgcn_mfma_f32_32x32x16_bf16(
              af[mi][kb], bfv[ni][kb], acc[mi][ni], 0, 0, 0);
    __syncthreads();
  }

  // C/D frag layout (m74/m101): col = lane&31, row = (reg&3)+8*(reg>>2)+4*(lane>>5)
  // Repack 32-row bands g=0..3 (block rows [g*32,(g+1)*32)): wave participates
  // iff wm+mi*32 == g*32 -> mi = g - (wm>>5).
  if (MODE == 0 || MODE == 1) {
    unsigned short(*rp)[136] = (unsigned short(*)[136])smem;
    unsigned short* C = (unsigned short*)Cout;
#pragma unroll
    for (int g = 0; g < 4; ++g) {
      int mi = g - (wm >> 5);
      __syncthreads();
      if (mi == 0 || mi == 1) {
#pragma unroll
        for (int ni = 0; ni < 2; ++ni)
#pragma unroll
          for (int reg = 0; reg < 16; ++reg) {
            int row = (reg & 3) + 8 * (reg >> 2) + rbase;
            rp[row][wn + ni * 32 + r31] = f2bf(acc[mi & 1][ni][reg]);
          }
      }
      __syncthreads();
#pragma unroll
      for (int j = 0; j < 2; ++j) {
        int off = j * 2048 + t * 8;          // elem in 32x128 band
        int lr = off >> 7, c = off & 127;
        int grow = m0 + g * 32 + lr;
        int gcol = n0 + c;
        u16x8 v = *(const u16x8*)&rp[lr][c];
        if (MODE == 1) {
          u16x8 xv = *(const u16x8*)&xs[(size_t)grow * ldc + gcol];
          float Dh = Dvec[gcol >> 6];
          u16x8 o;
#pragma unroll
          for (int e = 0; e < 8; ++e) o[e] = f2bf(bf2f(v[e]) + Dh * bf2f(xv[e]));
          *(u16x8*)&C[(size_t)grow * ldc + gcol] = o;
        } else {
          if (gcol < Nstore) *(u16x8*)&C[(size_t)grow * ldc + gcol] = v;
        }
      }
    }
  } else {
    float(*rpf)[136] = (float(*)[136])smem;  // 32*136*4 = 17408 B
    float* C = (float*)Cout;
    if (MODE == 2) C += (size_t)blockIdx.z * DS * DI;
#pragma unroll
    for (int g = 0; g < 4; ++g) {
      int mi = g - (wm >> 5);
      __syncthreads();
      if (mi == 0 || mi == 1) {
#pragma unroll
        for (int ni = 0; ni < 2; ++ni)
#pragma unroll
          for (int reg = 0; reg < 16; ++reg) {
            int row = (reg & 3) + 8 * (reg >> 2) + rbase;
            rpf[row][wn + ni * 32 + r31] = acc[mi & 1][ni][reg];
          }
      }
      __syncthreads();
#pragma unroll
      for (int j = 0; j < 4; ++j) {
        int off = j * 1024 + t * 4;          // elem in 32x128 band
        int lr = off >> 7, c = off & 127;
        int grow = m0 + g * 32 + lr;
        int gcol = n0 + c;
        float4 v = *(const float4*)&rpf[lr][c];
        *(float4*)&C[(size_t)grow * ldc + gcol] = v;
      }
    }
  }
}

// ---------------------------------------------------------------------------
// One merged cast dispatch. Regions (in 256-thread blocks of 4-elem quads):
//   [0, 8192):        x       (8192x1024 f32 -> bf16)
//   [8192, 12672):    W_in    (4384x1024 -> 4480x1024 bf16, pad rows zero)
//   [12672, 14720):   W_out   (1024x2048 f32 -> bf16)
// ---------------------------------------------------------------------------
__global__ __launch_bounds__(256)
void cast_all_kernel(const float* __restrict__ x, const float* __restrict__ W_in,
                     const float* __restrict__ W_out,
                     unsigned short* __restrict__ x_bf16,
                     unsigned short* __restrict__ win_bf16,
                     unsigned short* __restrict__ wout_bf16) {
  int b = blockIdx.x;
  int t = threadIdx.x;
  u16x4 o = (u16x4){0, 0, 0, 0};
  if (b < 8192) {
    size_t i4 = ((size_t)b * 256 + t) * 4;
    float4 v = *(const float4*)(x + i4);
    o.x = f2bf(v.x); o.y = f2bf(v.y); o.z = f2bf(v.z); o.w = f2bf(v.w);
    *(u16x4*)(x_bf16 + i4) = o;
  } else if (b < 12672) {
    size_t i4 = ((size_t)(b - 8192) * 256 + t) * 4;  // over 4480*1024
    int row = (int)(i4 >> 10);
    if (row < DPROJ) {
      float4 v = *(const float4*)(W_in + i4);
      o.x = f2bf(v.x); o.y = f2bf(v.y); o.z = f2bf(v.z); o.w = f2bf(v.w);
    }
    *(u16x4*)(win_bf16 + i4) = o;
  } else {
    size_t i4 = ((size_t)(b - 12672) * 256 + t) * 4;
    float4 v = *(const float4*)(W_out + i4);
    o.x = f2bf(v.x); o.y = f2bf(v.y); o.z = f2bf(v.z); o.w = f2bf(v.w);
    *(u16x4*)(wout_bf16 + i4) = o;
  }
}

// ---------------------------------------------------------------------------
// s[l,h] = dt * exp(-dt*exp(A_log[h])),  dt = softplus(zxb[l,4352+h]+dt_bias[h])
// ---------------------------------------------------------------------------
__global__ __launch_bounds__(256)
void dt_kernel(const unsigned short* __restrict__ zxb, const float* __restrict__ dt_bias,
               const float* __restrict__ A_log, float* __restrict__ s_out) {
  int idx = blockIdx.x * 256 + threadIdx.x;  // l*32 + h
  int l = idx >> 5, h = idx & 31;
  float v = bf2f(zxb[(size_t)l * DPROJ + (DI + CDIM) + h]) + dt_bias[h];
  float d = (v > 20.f) ? v : log1pf(expf(v));
  s_out[idx] = d * expf(-d * expf(A_log[h]));
}

// ---------------------------------------------------------------------------
// Fused conv+silu+transpose. Block = 64 channels x 64 l, 256 threads.
// ---------------------------------------------------------------------------
__global__ __launch_bounds__(256)
void conv_fused_kernel(const unsigned short* __restrict__ zxb,
                       const float* __restrict__ Wc,
                       const float* __restrict__ bc,
                       const float* __restrict__ svec,
                       unsigned short* __restrict__ xs,
                       unsigned short* __restrict__ cb,
                       unsigned short* __restrict__ OpT) {
  __shared__ unsigned short zt[67][66];
  __shared__ unsigned short ot[64][66];
  __shared__ float sl[64];
  const int c0 = blockIdx.x * 64;
  const int l0 = blockIdx.y * 64;
  const int t = threadIdx.x;
  for (int idx = t; idx < 67 * 16; idx += 256) {
    int row = idx >> 4;
    int colq = (idx & 15) * 4;
    int gl = l0 - 1 + row;
    u16x4 v = (u16x4){0, 0, 0, 0};
    if (gl >= 0 && gl < L_SEQ)
      v = *(const u16x4*)&zxb[(size_t)gl * DPROJ + DI + c0 + colq];
    *(u16x4*)&zt[row][colq] = v;
  }
  const bool isX = (c0 < DI);
  const bool isC = (c0 >= DI + DS);
  if (isX && t < 64) sl[t] = svec[(size_t)(l0 + t) * NH + (c0 >> 6)];
  const int c = t & 63;
  const int gc = c0 + c;
  const float4 wv = *(const float4*)&Wc[gc * 4];
  const float bias = bc[gc];
  const int lq = (t >> 6) * 16;
  __syncthreads();
#pragma unroll
  for (int i = 0; i < 16; ++i) {
    int ll = lq + i;
    float sacc = bias + bf2f(zt[ll][c]) * wv.x + bf2f(zt[ll + 1][c]) * wv.y +
                 bf2f(zt[ll + 2][c]) * wv.z + bf2f(zt[ll + 3][c]) * wv.w;
    float v = sacc / (1.f + expf(-sacc));
    int gl = l0 + ll;
    if (isC) {
      cb[(size_t)gl * DS + (gc - (DI + DS))] = f2bf(v);
    } else if (isX) {
      xs[(size_t)gl * DI + gc] = f2bf(v);
      ot[c][ll] = f2bf(v * sl[ll]);
    } else {
      ot[c][ll] = f2bf(v);
    }
  }
  if (!isC) {
    __syncthreads();
#pragma unroll
    for (int j = 0; j < 4; ++j) {
      int linear = j * 1024 + t * 4;
      int rr = linear >> 6;
      int lc = linear & 63;
      *(u16x4*)&OpT[(size_t)(c0 + rr) * L_SEQ + l0 + lc] = *(const u16x4*)&ot[rr][lc];
    }
  }
}

// ---------------------------------------------------------------------------
// Ht[p][n] = bf16( sum_z Ppart[z][n][p] )
// ---------------------------------------------------------------------------
__global__ __launch_bounds__(256)
void h_reduce_t_kernel(const float* __restrict__ P, unsigned short* __restrict__ Ht) {
  __shared__ float tile[32][65];
  const int bid = blockIdx.x;
  const int pt = bid & 31, ng = bid >> 5;
  const int t = threadIdx.x;
#pragma unroll
  for (int i = 0; i < 8; ++i) {
    int nl = i * 4 + (t >> 6);
    int n = ng * 32 + nl;
    int p = pt * 64 + (t & 63);
    float acc = 0.f;
#pragma unroll
    for (int z = 0; z < KSPLIT; ++z)
      acc += P[(size_t)z * (DS * DI) + (size_t)n * DI + p];
    tile[nl][t & 63] = acc;
  }
  __syncthreads();
#pragma unroll
  for (int j = 0; j < 8; ++j) {
    int linear = j * 256 + t;
    int pl = linear >> 5, nl = linear & 31;
    Ht[(size_t)(pt * 64 + pl) * DS + ng * 32 + nl] = f2bf(tile[nl][pl]);
  }
}

// ---------------------------------------------------------------------------
// LayerNorm over 2048 (bf16 y) + z-gate (bf16 z); bf16 yz into zxb [2048,4096)
// ---------------------------------------------------------------------------
__global__ __launch_bounds__(256)
void ln_mul_kernel(const unsigned short* __restrict__ ybuf, unsigned short* __restrict__ zxb,
                   const float* __restrict__ ln_w, const float* __restrict__ ln_b) {
  int l = blockIdx.x;
  int t = threadIdx.x;
  int c0 = t * 8;
  u16x8 yv = *(const u16x8*)&ybuf[(size_t)l * DI + c0];
  float vals[8];
  float s = 0.f, sq = 0.f;
#pragma unroll
  for (int i = 0; i < 8; ++i) {
    float v = bf2f(yv[i]);
    vals[i] = v;
    s += v;
    sq += v * v;
  }
#pragma unroll
  for (int off = 32; off > 0; off >>= 1) {
    s += __shfl_down(s, off, 64);
    sq += __shfl_down(sq, off, 64);
  }
  __shared__ float red[10];
  int wave = t >> 6, lane = t & 63;
  if (lane == 0) { red[wave] = s; red[4 + wave] = sq; }
  __syncthreads();
  if (t == 0) {
    float S = red[0] + red[1] + red[2] + red[3];
    float SQ = red[4] + red[5] + red[6] + red[7];
    float mu = S / (float)DI;
    red[8] = mu;
    red[9] = rsqrtf(SQ / (float)DI - mu * mu + 1e-5f);
  }
  __syncthreads();
  float mu = red[8], rstd = red[9];
  unsigned short* zrow = zxb + (size_t)l * DPROJ;
  u16x8 zv = *(const u16x8*)&zrow[c0];
  float4 w0 = *(const float4*)&ln_w[c0], w1 = *(const float4*)&ln_w[c0 + 4];
  float4 b0 = *(const float4*)&ln_b[c0], b1 = *(const float4*)&ln_b[c0 + 4];
  float w[8] = {w0.x, w0.y, w0.z, w0.w, w1.x, w1.y, w1.z, w1.w};
  float b[8] = {b0.x, b0.y, b0.z, b0.w, b1.x, b1.y, b1.z, b1.w};
  u16x8 o;
#pragma unroll
  for (int i = 0; i < 8; ++i) {
    float v = (vals[i] - mu) * rstd * w[i] + b[i];
    o[i] = f2bf(v * bf2f(zv[i]));
  }
  *(u16x8*)&zrow[DI + c0] = o;
}

// ---------------------------------------------------------------------------
extern "C" void kernel_launch(void* const* d_in, const int* in_sizes, int n_in,
                              void* d_out, int out_size, void* d_ws, size_t ws_size,
                              hipStream_t stream) {
  const float* x       = (const float*)d_in[0];
  const float* W_in    = (const float*)d_in[1];
  const float* W_conv  = (const float*)d_in[2];
  const float* b_conv  = (const float*)d_in[3];
  const float* dt_bias = (const float*)d_in[4];
  const float* A_log   = (const float*)d_in[5];
  const float* D_param = (const float*)d_in[6];
  const float* ln_w    = (const float*)d_in[7];
  const float* ln_b    = (const float*)d_in[8];
  const float* W_out   = (const float*)d_in[9];
  float* out = (float*)d_out;

  // ---- workspace layout (~183 MB) ----
  unsigned short* zxb = (unsigned short*)d_ws;           // L*4384 bf16
  unsigned short* xs   = zxb + (size_t)L_SEQ * DPROJ;    // L*2048 bf16
  unsigned short* cb   = xs + (size_t)L_SEQ * DI;        // L*128 bf16
  float* svec = (float*)(cb + (size_t)L_SEQ * DS);       // L*32 f32
  unsigned short* OpT = (unsigned short*)(svec + (size_t)L_SEQ * NH);  // 2176*8192 bf16
  float* Ppart = (float*)(OpT + (size_t)OPROWS * L_SEQ); // 32*128*2048 f32
  unsigned short* Ht = (unsigned short*)(Ppart + (size_t)KSPLIT * DS * DI);  // 2048*128
  unsigned short* wout_bf16 = Ht + (size_t)DI * DS;      // 1024*2048 bf16
  // aliases in OpT's dead windows:
  unsigned short* x_bf16   = OpT;                        // casts..GEMM1 (16 MB)
  unsigned short* win_bf16 = OpT + (size_t)L_SEQ * DM;   // casts..GEMM1 (9.2 MB)
  unsigned short* ybuf     = OpT;                        // Y-GEMM..ln_mul (33.5 MB)

  // 0) all casts in one dispatch
  cast_all_kernel<<<14720, 256, 0, stream>>>(x, W_in, W_out, x_bf16, win_bf16,
                                             wout_bf16);

  // 1) zxb = bf16( x @ W_in^T )  (M=8192, N=4480 pad, K=1024)
  gemm_bt_mfma<0><<<dim3(NPAD_IN / 128, L_SEQ / 128), 256, 0, stream>>>(
      x_bf16, DM, win_bf16, DM, zxb, DPROJ, DM, DPROJ, nullptr, nullptr);

  // 2) s = a*dt
  dt_kernel<<<(L_SEQ * NH) / 256, 256, 0, stream>>>(zxb, dt_bias, A_log, svec);

  // 3) conv + silu + transpose-pack (clobbers x_bf16/win_bf16 — dead)
  conv_fused_kernel<<<dim3(CDIM / 64, L_SEQ / 64), 256, 0, stream>>>(
      zxb, W_conv, b_conv, svec, xs, cb, OpT);

  // 4) Hcat = B^T @ Vs : M=128, N=2048, K=8192, split-K=32 (repacked f32 out)
  gemm_bt_mfma<2><<<dim3(DI / 128, 1, KSPLIT), 256, 0, stream>>>(
      OpT + (size_t)DI * L_SEQ, L_SEQ, OpT, L_SEQ, Ppart, DI, L_SEQ, DI,
      nullptr, nullptr);

  // 5) reduce partials + transpose -> Ht (2048 x 128 bf16)
  h_reduce_t_kernel<<<128, 256, 0, stream>>>(Ppart, Ht);

  // 6) y = C @ Hcat + D*x_ssm : M=8192, N=2048, K=128, bf16 repacked out
  gemm_bt_mfma<1><<<dim3(DI / 128, L_SEQ / 128), 256, 0, stream>>>(
      cb, DS, Ht, DS, ybuf, DI, DS, DI, xs, D_param);

  // 7) LN + z-gate -> bf16 yz into zxb cols [2048,4096)
  ln_mul_kernel<<<L_SEQ, 256, 0, stream>>>(ybuf, zxb, ln_w, ln_b);

  // 8) out = yz @ W_out^T : M=8192, N=1024, K=2048 (repacked f32 out)
  gemm_bt_mfma<3><<<dim3(DM / 128, L_SEQ / 128), 256, 0, stream>>>(
      zxb + DI, DPROJ, wout_bf16, DI, out, DM, DI, DM, nullptr, nullptr);
}